// Round 10
// baseline (571.677 us; speedup 1.0000x reference)
//
#include <hip/hip_runtime.h>

typedef unsigned short u16;
typedef __attribute__((ext_vector_type(8))) short short8;
typedef __attribute__((ext_vector_type(4))) float f32x4;

#define D_DIM   1024
#define ROWS    32768   // B*T = 4*8192
#define T_DIM   8192
#define BM      256
#define BN      256
#define BK      64

__device__ __forceinline__ float bf2f(u16 u) {
    union { unsigned int i; float f; } c; c.i = ((unsigned int)u) << 16; return c.f;
}
__device__ __forceinline__ u16 f2bf(float f) {
    union { float f; unsigned int i; } c; c.f = f;
    unsigned int r = c.i + 0x7FFF + ((c.i >> 16) & 1);   // RNE
    return (u16)(r >> 16);
}

#define GLL16(gp, lp) \
    __builtin_amdgcn_global_load_lds((const __attribute__((address_space(1))) void*)(gp), \
                                     (__attribute__((address_space(3))) void*)(lp), 16, 0, 0)

// ---------------- Kernel 0: merged prep ----------------
// blocks [0,2048): grid-stride x fp32 -> xb bf16 (8 vec8 chunks/thread) + zero-fill stats;
// blocks [2048,5120): W transpose (one 32x32 tile each).
__global__ __launch_bounds__(256)
void prep(const float* __restrict__ x, u16* __restrict__ xb,
          const float* __restrict__ W, u16* __restrict__ WT,
          float* __restrict__ zstats) {
    __shared__ u16 tile[32][34];
    if (blockIdx.x < 2048) {
        // qssq (32768) + kssq (32768) + kv (4096) = 69632 floats = 272 x 256
        if (blockIdx.x < 272)
            zstats[blockIdx.x * 256 + threadIdx.x] = 0.0f;
        size_t tidg = (size_t)blockIdx.x * 256 + threadIdx.x;   // 524288 threads
        #pragma unroll
        for (int it = 0; it < 8; ++it) {
            size_t idx = (tidg + (size_t)it * 524288) * 8;      // vec8 units, coalesced
            float4 f0 = *reinterpret_cast<const float4*>(x + idx);
            float4 f1 = *reinterpret_cast<const float4*>(x + idx + 4);
            short8 v;
            v[0] = (short)f2bf(f0.x); v[1] = (short)f2bf(f0.y);
            v[2] = (short)f2bf(f0.z); v[3] = (short)f2bf(f0.w);
            v[4] = (short)f2bf(f1.x); v[5] = (short)f2bf(f1.y);
            v[6] = (short)f2bf(f1.z); v[7] = (short)f2bf(f1.w);
            *reinterpret_cast<short8*>(xb + idx) = v;
        }
    } else {
        int bx2 = blockIdx.x - 2048;           // 0..3071 = 96 x 32
        int nb = (bx2 % 96) * 32;
        int kb = (bx2 / 96) * 32;
        int tx = threadIdx.x & 31;
        int ty = threadIdx.x >> 5;             // 0..7
        #pragma unroll
        for (int i = 0; i < 32; i += 8)
            tile[ty + i][tx] = f2bf(W[(size_t)(kb + ty + i) * 3072 + nb + tx]);
        __syncthreads();
        #pragma unroll
        for (int i = 0; i < 32; i += 8)
            WT[(size_t)(nb + ty + i) * D_DIM + kb + tx] = tile[tx][ty + i];
    }
}

// ---------------- Kernel 2: 256x256-tile GEMM (exact round-5/9 measured-best) ----------------
// C[row, col] = sum_k xb[row,k] * WT[col,k] + bqkv[col]
// by<4: q -> qb + qssq ; by 4..7: k -> kvb + kssq ; by>=8: v -> kvb
// Round-2 phase protocol, merged tile-end/boundary barrier, XCD-bijective swizzle.
__global__ __launch_bounds__(512)
void gemm_k(const u16* __restrict__ xb, const u16* __restrict__ WT,
            const float* __restrict__ bqkv,
            u16* __restrict__ qb, u16* __restrict__ kvb,
            float* __restrict__ qssq, float* __restrict__ kssq)
{
    __shared__ __align__(16) u16 a_sh[2 * 2 * 8192];   // [db][half][128*64]
    __shared__ __align__(16) u16 b_sh[2 * 2 * 8192];

    const int tid  = threadIdx.x;
    const int lane = tid & 63;
    const int w    = tid >> 6;      // wave 0..7
    const int l15  = lane & 15;
    const int quad = lane >> 4;     // 0..3
    const int wm   = w >> 2;        // 0..1 : 128-row half
    const int wn   = w & 3;         // 0..3 : 64-col quarter

    // ---- XCD-aware bijective swizzle ----
    const int n    = blockIdx.x + 128 * blockIdx.y;
    const int xcd  = n & 7;
    const int slot = n >> 3;                          // 0..191
    const int gg   = slot / 48;                       // 0..3
    const int rr   = slot % 48;
    const int bx   = xcd + 8 * (gg * 4 + (rr & 3));   // 0..127
    const int by   = rr >> 2;                         // 0..11
    const int r0   = bx * BM;
    const int c0   = by * BN;

    // ---- staging source pointers ----
    const u16* pA[2];
    const u16* pB[2];
    u16* ldsA[2];
    u16* ldsB[2];
    #pragma unroll
    for (int i = 0; i < 2; ++i) {
        int s    = i * 64 + (tid >> 3);             // chunk slot-row 0..127
        int gsrc = (tid & 7) ^ (s & 7);             // pre-swizzled 16B group
        int rA   = (s & 63) + 128 * (s >> 6);       // chunk-local -> global row offset (h=0)
        int cB   = (s & 31) + 64 * (s >> 5);        // chunk-local -> global col offset (h=0)
        pA[i] = xb + (size_t)(r0 + rA) * D_DIM + gsrc * 8;
        pB[i] = WT + (size_t)(c0 + cB) * D_DIM + gsrc * 8;
        ldsA[i] = a_sh + i * 4096 + w * 512;        // wave-uniform
        ldsB[i] = b_sh + i * 4096 + w * 512;
    }

#define STAGE_A(kt, H, DBs) do { \
    GLL16(pA[0] + (size_t)(H) * 65536 + (kt) * 64, ldsA[0] + (DBs) * 16384 + (H) * 8192); \
    GLL16(pA[1] + (size_t)(H) * 65536 + (kt) * 64, ldsA[1] + (DBs) * 16384 + (H) * 8192); \
} while (0)
#define STAGE_B(kt, H, DBs) do { \
    GLL16(pB[0] + (size_t)(H) * 32768 + (kt) * 64, ldsB[0] + (DBs) * 16384 + (H) * 8192); \
    GLL16(pB[1] + (size_t)(H) * 32768 + (kt) * 64, ldsB[1] + (DBs) * 16384 + (H) * 8192); \
} while (0)

    // ---- fragment read bases ----
    const int g0o = (quad ^ (l15 & 7)) * 8;
    const int g1o = ((quad + 4) ^ (l15 & 7)) * 8;
    const u16* aRdB = a_sh + (wm * 64 + l15) * 64;
    const u16* bRdB = b_sh + (wn * 32 + l15) * 64;

    f32x4 acc[8][4];
    #pragma unroll
    for (int mt = 0; mt < 8; ++mt)
        #pragma unroll
        for (int nt = 0; nt < 4; ++nt) acc[mt][nt] = (f32x4)(0.0f);

#define LOAD_A(MH, DBl) do { \
    _Pragma("unroll") for (int mtq = 0; mtq < 4; ++mtq) { \
        aF[mtq][0] = *reinterpret_cast<const short8*>(aRdB + (DBl) * 16384 + (MH) * 8192 + mtq * 1024 + g0o); \
        aF[mtq][1] = *reinterpret_cast<const short8*>(aRdB + (DBl) * 16384 + (MH) * 8192 + mtq * 1024 + g1o); \
    } } while (0)
#define LOAD_B(NH, DBl) do { \
    _Pragma("unroll") for (int ntq = 0; ntq < 2; ++ntq) { \
        bF[ntq][0] = *reinterpret_cast<const short8*>(bRdB + (DBl) * 16384 + (NH) * 8192 + ntq * 1024 + g0o); \
        bF[ntq][1] = *reinterpret_cast<const short8*>(bRdB + (DBl) * 16384 + (NH) * 8192 + ntq * 1024 + g1o); \
    } } while (0)

#define MFMA_Q(MH, NH) do { \
    __builtin_amdgcn_s_setprio(1); \
    _Pragma("unroll") for (int ks = 0; ks < 2; ++ks) \
        _Pragma("unroll") for (int mtq = 0; mtq < 4; ++mtq) \
            _Pragma("unroll") for (int ntq = 0; ntq < 2; ++ntq) \
                acc[(MH) * 4 + mtq][(NH) * 2 + ntq] = __builtin_amdgcn_mfma_f32_16x16x32_bf16( \
                    aF[mtq][ks], bF[ntq][ks], acc[(MH) * 4 + mtq][(NH) * 2 + ntq], 0, 0, 0); \
    __builtin_amdgcn_s_setprio(0); \
} while (0)

#define PH_SYNC() do { \
    __builtin_amdgcn_s_barrier(); \
    asm volatile("s_waitcnt lgkmcnt(0)" ::: "memory"); \
    __builtin_amdgcn_sched_barrier(0); \
} while (0)

#define TILE(tExpr, DBc, ENDWAIT) do { \
    const int t_ = (tExpr); \
    short8 aF[4][2], bF[2][2]; \
    /* P1: (mh0,nh0) */ \
    LOAD_A(0, DBc); LOAD_B(0, DBc); \
    if (t_ < 15) STAGE_A(t_ + 1, 1, (DBc) ^ 1); \
    PH_SYNC(); MFMA_Q(0, 0); \
    __builtin_amdgcn_s_barrier(); \
    /* P2: (mh0,nh1) */ \
    LOAD_B(1, DBc); \
    if (t_ < 15) STAGE_B(t_ + 1, 1, (DBc) ^ 1); \
    PH_SYNC(); MFMA_Q(0, 1); \
    __builtin_amdgcn_s_barrier(); \
    /* P3: (mh1,nh0) */ \
    LOAD_A(1, DBc); LOAD_B(0, DBc); \
    if (t_ < 14) STAGE_A(t_ + 2, 0, DBc); \
    PH_SYNC(); MFMA_Q(1, 0); \
    __builtin_amdgcn_s_barrier(); \
    /* P4: (mh1,nh1) — tile-end barrier merged with boundary */ \
    LOAD_B(1, DBc); \
    if (t_ < 14) STAGE_B(t_ + 2, 0, DBc); \
    PH_SYNC(); MFMA_Q(1, 1); \
    __builtin_amdgcn_sched_barrier(0); \
    asm volatile(ENDWAIT ::: "memory"); \
    __builtin_amdgcn_s_barrier(); \
    __builtin_amdgcn_sched_barrier(0); \
} while (0)

    // ---- prologue ----
    STAGE_A(0, 0, 0); STAGE_B(0, 0, 0);
    STAGE_A(0, 1, 0); STAGE_B(0, 1, 0);
    STAGE_A(1, 0, 1); STAGE_B(1, 0, 1);
    asm volatile("s_waitcnt vmcnt(4)" ::: "memory");
    __builtin_amdgcn_sched_barrier(0);
    __builtin_amdgcn_s_barrier();
    __builtin_amdgcn_sched_barrier(0);

    #pragma unroll 1
    for (int tt = 0; tt < 7; ++tt) {
        TILE(2 * tt,     0, "s_waitcnt vmcnt(4)");
        TILE(2 * tt + 1, 1, "s_waitcnt vmcnt(4)");
    }
    TILE(14, 0, "s_waitcnt vmcnt(0)");
    TILE(15, 1, "s_waitcnt vmcnt(0)");

    // ---- epilogue: bias ----
    float bcol[4];
    #pragma unroll
    for (int nt = 0; nt < 4; ++nt)
        bcol[nt] = bqkv[c0 + wn * 64 + nt * 16 + l15];
    #pragma unroll
    for (int mt = 0; mt < 8; ++mt)
        #pragma unroll
        for (int nt = 0; nt < 4; ++nt)
            #pragma unroll
            for (int rg = 0; rg < 4; ++rg) acc[mt][nt][rg] += bcol[nt];

    // ---- row sum-of-squares (q and k blocks only) ----
    if (by < 8) {
        float* ssq = (by < 4) ? qssq : kssq;
        #pragma unroll
        for (int mt = 0; mt < 8; ++mt)
            #pragma unroll
            for (int rg = 0; rg < 4; ++rg) {
                float s = acc[mt][0][rg] * acc[mt][0][rg]
                        + acc[mt][1][rg] * acc[mt][1][rg]
                        + acc[mt][2][rg] * acc[mt][2][rg]
                        + acc[mt][3][rg] * acc[mt][3][rg];
                #pragma unroll
                for (int m = 1; m < 16; m <<= 1) s += __shfl_xor(s, m, 16);
                if (l15 == 0)
                    atomicAdd(&ssq[r0 + wm * 128 + mt * 16 + quad * 4 + rg], s);
            }
    }

    // ---- store bf16 ----
    u16* dst;
    int ldc, cb;
    if (by < 4) { dst = qb;  ldc = 1024; cb = c0; }
    else        { dst = kvb; ldc = 2048; cb = c0 - 1024; }
    #pragma unroll
    for (int mt = 0; mt < 8; ++mt)
        #pragma unroll
        for (int nt = 0; nt < 4; ++nt) {
            int col = cb + wn * 64 + nt * 16 + l15;
            #pragma unroll
            for (int rg = 0; rg < 4; ++rg) {
                int row = r0 + wm * 128 + mt * 16 + quad * 4 + rg;
                dst[(size_t)row * ldc + col] = f2bf(acc[mt][nt][rg]);
            }
        }
}

// ---------------- Kernel 3: kv[b,d] = sum_t k*v*rsqrt(kssq) ----------------
// 128 t-chunks of 64 rows x 4 batches = 512 blocks, 512 threads (4 row-phases x 128 d),
// LDS combine, one atomic round per block.
__global__ __launch_bounds__(512)
void kv_reduce(const u16* __restrict__ kvb, const float* __restrict__ kssq,
               float* __restrict__ kv)
{
    __shared__ float red[3][1024];
    int d  = (threadIdx.x & 127) * 8;
    int rp = threadIdx.x >> 7;                 // 0..3
    int b  = blockIdx.y;                       // 0..3
    int t0 = blockIdx.x * 64;                  // 128 t-chunks of 64 rows
    float a[8];
    #pragma unroll
    for (int e = 0; e < 8; ++e) a[e] = 0.0f;
    #pragma unroll 4
    for (int r = rp; r < 64; r += 4) {
        int row = b * T_DIM + t0 + r;
        float kin = rsqrtf(kssq[row]);
        short8 k8 = *reinterpret_cast<const short8*>(kvb + (size_t)row * 2048 + d);
        short8 v8 = *reinterpret_cast<const short8*>(kvb + (size_t)row * 2048 + 1024 + d);
        #pragma unroll
        for (int e = 0; e < 8; ++e)
            a[e] += bf2f((u16)k8[e]) * bf2f((u16)v8[e]) * kin;
    }
    if (rp) {
        #pragma unroll
        for (int e = 0; e < 8; ++e) red[rp - 1][d + e] = a[e];
    }
    __syncthreads();
    if (!rp) {
        #pragma unroll
        for (int e = 0; e < 8; ++e)
            atomicAdd(&kv[b * D_DIM + d + e],
                      a[e] + red[0][d + e] + red[1][d + e] + red[2][d + e]);
    }
}

// ---------------- Kernel 4: out = q*rsqrt(qssq)*kv*scale + bias (fp32) ----------------
// 2048 blocks x 256 threads, grid-stride x8; vectorized kv/scale/bias reads.
__global__ __launch_bounds__(256)
void finalize(const u16* __restrict__ qb, const float* __restrict__ qssq,
              const float* __restrict__ kv, const float* __restrict__ scale,
              const float* __restrict__ bias, float* __restrict__ out)
{
    size_t tidg = (size_t)blockIdx.x * 256 + threadIdx.x;      // 524288 threads
    #pragma unroll
    for (int it = 0; it < 8; ++it) {
        size_t idx = tidg + (size_t)it * 524288;               // vec8 index
        int row = (int)(idx >> 7);
        int dv  = ((int)idx & 127) * 8;
        int b   = row >> 13;
        float qi = rsqrtf(qssq[row]);
        short8 qv = *reinterpret_cast<const short8*>(qb + (size_t)row * D_DIM + dv);
        float4 kv0 = *reinterpret_cast<const float4*>(kv + b * D_DIM + dv);
        float4 kv1 = *reinterpret_cast<const float4*>(kv + b * D_DIM + dv + 4);
        float4 s0  = *reinterpret_cast<const float4*>(scale + dv);
        float4 s1  = *reinterpret_cast<const float4*>(scale + dv + 4);
        float4 b0  = *reinterpret_cast<const float4*>(bias + dv);
        float4 b1  = *reinterpret_cast<const float4*>(bias + dv + 4);
        float4 o0, o1;
        o0.x = bf2f((u16)qv[0]) * qi * kv0.x * s0.x + b0.x;
        o0.y = bf2f((u16)qv[1]) * qi * kv0.y * s0.y + b0.y;
        o0.z = bf2f((u16)qv[2]) * qi * kv0.z * s0.z + b0.z;
        o0.w = bf2f((u16)qv[3]) * qi * kv0.w * s0.w + b0.w;
        o1.x = bf2f((u16)qv[4]) * qi * kv1.x * s1.x + b1.x;
        o1.y = bf2f((u16)qv[5]) * qi * kv1.y * s1.y + b1.y;
        o1.z = bf2f((u16)qv[6]) * qi * kv1.z * s1.z + b1.z;
        o1.w = bf2f((u16)qv[7]) * qi * kv1.w * s1.w + b1.w;
        float* op = out + (size_t)row * D_DIM + dv;
        *reinterpret_cast<float4*>(op)     = o0;
        *reinterpret_cast<float4*>(op + 4) = o1;
    }
}

extern "C" void kernel_launch(void* const* d_in, const int* in_sizes, int n_in,
                              void* d_out, int out_size, void* d_ws, size_t ws_size,
                              hipStream_t stream) {
    const float* x     = (const float*)d_in[0];
    const float* W     = (const float*)d_in[1];
    const float* bqkv  = (const float*)d_in[2];
    const float* scale = (const float*)d_in[3];
    const float* bias  = (const float*)d_in[4];
    float* out = (float*)d_out;

    // d_out doubles as scratch until finalize: xb (64 MB) + WT (6 MB) < 128 MB
    u16* xb = (u16*)d_out;
    u16* WT = (u16*)((char*)d_out + 67108864);

    char* ws = (char*)d_ws;
    u16*   qb   = (u16*)ws;                         //  67,108,864 B
    u16*   kvb  = (u16*)(ws + 67108864);            // 134,217,728 B
    float* qssq = (float*)(ws + 201326592);         //     131,072 B
    float* kssq = (float*)(ws + 201457664);         //     131,072 B
    float* kv   = (float*)(ws + 201588736);         //      16,384 B
    // qssq/kssq/kv contiguous: zero-filled by prep (272*256 floats)

    prep     <<<dim3(2048 + 3072), dim3(256), 0, stream>>>(x, xb, W, WT, qssq);
    gemm_k   <<<dim3(ROWS / BM, 12), dim3(512), 0, stream>>>(xb, WT, bqkv, qb, kvb, qssq, kssq);
    kv_reduce<<<dim3(T_DIM / 64, 4), dim3(512), 0, stream>>>(kvb, kssq, kv);
    finalize <<<dim3(2048), dim3(256), 0, stream>>>(qb, qssq, kv, scale, bias, out);
}

// Round 11
// 549.010 us; speedup vs baseline: 1.0413x; 1.0413x over previous
//
#include <hip/hip_runtime.h>

typedef unsigned short u16;
typedef __attribute__((ext_vector_type(8))) short short8;
typedef __attribute__((ext_vector_type(4))) float f32x4;

#define D_DIM   1024
#define ROWS    32768   // B*T = 4*8192
#define T_DIM   8192
#define BM      256
#define BN      256
#define BK      64

__device__ __forceinline__ float bf2f(u16 u) {
    union { unsigned int i; float f; } c; c.i = ((unsigned int)u) << 16; return c.f;
}
__device__ __forceinline__ u16 f2bf(float f) {
    union { float f; unsigned int i; } c; c.f = f;
    unsigned int r = c.i + 0x7FFF + ((c.i >> 16) & 1);   // RNE
    return (u16)(r >> 16);
}

#define GLL16(gp, lp) \
    __builtin_amdgcn_global_load_lds((const __attribute__((address_space(1))) void*)(gp), \
                                     (__attribute__((address_space(3))) void*)(lp), 16, 0, 0)

// ---------------- Kernel 0: merged prep (R9 measured form) ----------------
// blocks [0,16384): x fp32 -> xb bf16 (+ zero-fill stats); blocks >=16384: W transpose.
__global__ void prep(const float* __restrict__ x, u16* __restrict__ xb,
                     const float* __restrict__ W, u16* __restrict__ WT,
                     float* __restrict__ zstats) {
    __shared__ u16 tile[32][34];
    if (blockIdx.x < 16384) {
        size_t idx = ((size_t)blockIdx.x * 256 + threadIdx.x) * 8;
        float4 f0 = *reinterpret_cast<const float4*>(x + idx);
        float4 f1 = *reinterpret_cast<const float4*>(x + idx + 4);
        short8 v;
        v[0] = (short)f2bf(f0.x); v[1] = (short)f2bf(f0.y);
        v[2] = (short)f2bf(f0.z); v[3] = (short)f2bf(f0.w);
        v[4] = (short)f2bf(f1.x); v[5] = (short)f2bf(f1.y);
        v[6] = (short)f2bf(f1.z); v[7] = (short)f2bf(f1.w);
        *reinterpret_cast<short8*>(xb + idx) = v;
        // qssq (32768) + kssq (32768) + kv (4096) = 69632 floats = 272 x 256
        if (blockIdx.x < 272)
            zstats[blockIdx.x * 256 + threadIdx.x] = 0.0f;
    } else {
        int bx2 = blockIdx.x - 16384;          // 0..3071 = 96 x 32
        int nb = (bx2 % 96) * 32;
        int kb = (bx2 / 96) * 32;
        int tx = threadIdx.x & 31;
        int ty = threadIdx.x >> 5;             // 0..7
        #pragma unroll
        for (int i = 0; i < 32; i += 8)
            tile[ty + i][tx] = f2bf(W[(size_t)(kb + ty + i) * 3072 + nb + tx]);
        __syncthreads();
        #pragma unroll
        for (int i = 0; i < 32; i += 8)
            WT[(size_t)(nb + ty + i) * D_DIM + kb + tx] = tile[tx][ty + i];
    }
}

// ---------------- Kernel 2: 256x256-tile GEMM, upfront-read pipelined 4-phase ----------------
// C[row, col] = sum_k xb[row,k] * WT[col,k] + bqkv[col]
// by<4: q -> qb + qssq ; by 4..7: k -> kvb + kssq ; by>=8: v -> kvb
//
// NEW schedule: all 24 ds_read_b128 of a K-tile issued at tile start (order pinned in
// 4 groups by sched_barrier(0)); MFMA relies on compiler's counted lgkm waits; ONE
// barrier per phase. Stage stream and vmcnt ledger identical to the verified R2/R5
// scheme (q0:A1(t+1)->!DB, q1:B1(t+1)->!DB, q2:A0(t+2)->DBc, q3:B0(t+2)->DBc;
// boundary vmcnt(4), tail vmcnt(0)). WAR safety: DS completes in-order per wave, so
// q1's MFMA (group-2 regs) implies reads 1-16 drained -> barrier -> q2's A0-stage safe;
// q2's MFMA (group-3) + barrier -> q3's B0-stage safe; tile-end lgkmcnt(0) covers the
// next tile's !DB stages (readers were this tile's groups 3/4).
__global__ __launch_bounds__(512)
void gemm_k(const u16* __restrict__ xb, const u16* __restrict__ WT,
            const float* __restrict__ bqkv,
            u16* __restrict__ qb, u16* __restrict__ kvb,
            float* __restrict__ qssq, float* __restrict__ kssq)
{
    __shared__ __align__(16) u16 a_sh[2 * 2 * 8192];   // [db][half][128*64]
    __shared__ __align__(16) u16 b_sh[2 * 2 * 8192];

    const int tid  = threadIdx.x;
    const int lane = tid & 63;
    const int w    = tid >> 6;      // wave 0..7
    const int l15  = lane & 15;
    const int quad = lane >> 4;     // 0..3
    const int wm   = w >> 2;        // 0..1 : 128-row half
    const int wn   = w & 3;         // 0..3 : 64-col quarter

    // ---- XCD-aware bijective swizzle ----
    const int n    = blockIdx.x + 128 * blockIdx.y;
    const int xcd  = n & 7;
    const int slot = n >> 3;                          // 0..191
    const int gg   = slot / 48;                       // 0..3
    const int rr   = slot % 48;
    const int bx   = xcd + 8 * (gg * 4 + (rr & 3));   // 0..127
    const int by   = rr >> 2;                         // 0..11
    const int r0   = bx * BM;
    const int c0   = by * BN;

    // ---- staging source pointers ----
    const u16* pA[2];
    const u16* pB[2];
    u16* ldsA[2];
    u16* ldsB[2];
    #pragma unroll
    for (int i = 0; i < 2; ++i) {
        int s    = i * 64 + (tid >> 3);             // chunk slot-row 0..127
        int gsrc = (tid & 7) ^ (s & 7);             // pre-swizzled 16B group
        int rA   = (s & 63) + 128 * (s >> 6);       // chunk-local -> global row offset (h=0)
        int cB   = (s & 31) + 64 * (s >> 5);        // chunk-local -> global col offset (h=0)
        pA[i] = xb + (size_t)(r0 + rA) * D_DIM + gsrc * 8;
        pB[i] = WT + (size_t)(c0 + cB) * D_DIM + gsrc * 8;
        ldsA[i] = a_sh + i * 4096 + w * 512;        // wave-uniform
        ldsB[i] = b_sh + i * 4096 + w * 512;
    }

#define STAGE_A(kt, H, DBs) do { \
    GLL16(pA[0] + (size_t)(H) * 65536 + (kt) * 64, ldsA[0] + (DBs) * 16384 + (H) * 8192); \
    GLL16(pA[1] + (size_t)(H) * 65536 + (kt) * 64, ldsA[1] + (DBs) * 16384 + (H) * 8192); \
} while (0)
#define STAGE_B(kt, H, DBs) do { \
    GLL16(pB[0] + (size_t)(H) * 32768 + (kt) * 64, ldsB[0] + (DBs) * 16384 + (H) * 8192); \
    GLL16(pB[1] + (size_t)(H) * 32768 + (kt) * 64, ldsB[1] + (DBs) * 16384 + (H) * 8192); \
} while (0)

    // ---- fragment read bases ----
    const int g0o = (quad ^ (l15 & 7)) * 8;          // ks=0 swizzled k-group offset (u16)
    const int g1o = ((quad + 4) ^ (l15 & 7)) * 8;    // ks=1
    const u16* aRdB = a_sh + (wm * 64 + l15) * 64;
    const u16* bRdB = b_sh + (wn * 32 + l15) * 64;

    f32x4 acc[8][4];
    #pragma unroll
    for (int mt = 0; mt < 8; ++mt)
        #pragma unroll
        for (int nt = 0; nt < 4; ++nt) acc[mt][nt] = (f32x4)(0.0f);

#define RD_A(dst, MH, GO, DBl) do { \
    _Pragma("unroll") for (int mtq = 0; mtq < 4; ++mtq) \
        dst[mtq] = *reinterpret_cast<const short8*>( \
            aRdB + (DBl) * 16384 + (MH) * 8192 + mtq * 1024 + (GO)); \
} while (0)
#define RD_B(dst, GO, DBl) do { \
    _Pragma("unroll") for (int nt = 0; nt < 4; ++nt) \
        dst[nt] = *reinterpret_cast<const short8*>( \
            bRdB + (DBl) * 16384 + (nt >> 1) * 8192 + (nt & 1) * 1024 + (GO)); \
} while (0)

#define MFMAP(MH, A_, B_) do { \
    __builtin_amdgcn_s_setprio(1); \
    _Pragma("unroll") for (int mtq = 0; mtq < 4; ++mtq) \
        _Pragma("unroll") for (int nt = 0; nt < 4; ++nt) \
            acc[(MH) * 4 + mtq][nt] = __builtin_amdgcn_mfma_f32_16x16x32_bf16( \
                A_[mtq], B_[nt], acc[(MH) * 4 + mtq][nt], 0, 0, 0); \
    __builtin_amdgcn_s_setprio(0); \
} while (0)

#define TILE(tExpr, DBc, ENDWAIT) do { \
    const int t_ = (tExpr); \
    short8 aQ0[4], bQ0[4], aQ1[4], bQ1[4], aQ2[4], aQ3[4]; \
    /* group 1: q0 operands */ \
    RD_A(aQ0, 0, g0o, DBc); RD_B(bQ0, g0o, DBc); \
    __builtin_amdgcn_sched_barrier(0); \
    /* group 2: q1 operands */ \
    RD_A(aQ1, 0, g1o, DBc); RD_B(bQ1, g1o, DBc); \
    __builtin_amdgcn_sched_barrier(0); \
    /* q0: stage A1(t+1) -> !DB; issue group 3; MFMA (compiler-counted lgkm wait) */ \
    if (t_ < 15) STAGE_A(t_ + 1, 1, (DBc) ^ 1); \
    RD_A(aQ2, 1, g0o, DBc); \
    __builtin_amdgcn_sched_barrier(0); \
    MFMAP(0, aQ0, bQ0); \
    __builtin_amdgcn_s_barrier(); \
    /* q1: stage B1(t+1) -> !DB; issue group 4 */ \
    if (t_ < 15) STAGE_B(t_ + 1, 1, (DBc) ^ 1); \
    RD_A(aQ3, 1, g1o, DBc); \
    __builtin_amdgcn_sched_barrier(0); \
    MFMAP(0, aQ1, bQ1); \
    __builtin_amdgcn_s_barrier(); \
    /* q2: stage A0(t+2) -> DBc (readers 1-16 drained block-wide); B ks0 reg-reuse */ \
    if (t_ < 14) STAGE_A(t_ + 2, 0, DBc); \
    MFMAP(1, aQ2, bQ0); \
    __builtin_amdgcn_s_barrier(); \
    /* q3: stage B0(t+2) -> DBc; B ks1 reg-reuse; combined boundary wait */ \
    if (t_ < 14) STAGE_B(t_ + 2, 0, DBc); \
    MFMAP(1, aQ3, bQ1); \
    __builtin_amdgcn_sched_barrier(0); \
    asm volatile(ENDWAIT ::: "memory"); \
    __builtin_amdgcn_s_barrier(); \
    __builtin_amdgcn_sched_barrier(0); \
} while (0)

    // ---- prologue: tile0 fully, tile1 first halves; boundary for tile 0 ----
    STAGE_A(0, 0, 0); STAGE_B(0, 0, 0);
    STAGE_A(0, 1, 0); STAGE_B(0, 1, 0);
    STAGE_A(1, 0, 1); STAGE_B(1, 0, 1);
    asm volatile("s_waitcnt vmcnt(4)" ::: "memory");
    __builtin_amdgcn_sched_barrier(0);
    __builtin_amdgcn_s_barrier();
    __builtin_amdgcn_sched_barrier(0);

    #pragma unroll 1
    for (int tt = 0; tt < 7; ++tt) {
        TILE(2 * tt,     0, "s_waitcnt vmcnt(4) lgkmcnt(0)");
        TILE(2 * tt + 1, 1, "s_waitcnt vmcnt(4) lgkmcnt(0)");
    }
    TILE(14, 0, "s_waitcnt vmcnt(0) lgkmcnt(0)");
    TILE(15, 1, "s_waitcnt vmcnt(0) lgkmcnt(0)");

    // ---- epilogue: bias ----
    float bcol[4];
    #pragma unroll
    for (int nt = 0; nt < 4; ++nt)
        bcol[nt] = bqkv[c0 + wn * 64 + nt * 16 + l15];
    #pragma unroll
    for (int mt = 0; mt < 8; ++mt)
        #pragma unroll
        for (int nt = 0; nt < 4; ++nt)
            #pragma unroll
            for (int rg = 0; rg < 4; ++rg) acc[mt][nt][rg] += bcol[nt];

    // ---- row sum-of-squares (q and k blocks only) ----
    if (by < 8) {
        float* ssq = (by < 4) ? qssq : kssq;
        #pragma unroll
        for (int mt = 0; mt < 8; ++mt)
            #pragma unroll
            for (int rg = 0; rg < 4; ++rg) {
                float s = acc[mt][0][rg] * acc[mt][0][rg]
                        + acc[mt][1][rg] * acc[mt][1][rg]
                        + acc[mt][2][rg] * acc[mt][2][rg]
                        + acc[mt][3][rg] * acc[mt][3][rg];
                #pragma unroll
                for (int m = 1; m < 16; m <<= 1) s += __shfl_xor(s, m, 16);
                if (l15 == 0)
                    atomicAdd(&ssq[r0 + wm * 128 + mt * 16 + quad * 4 + rg], s);
            }
    }

    // ---- store bf16 ----
    u16* dst;
    int ldc, cb;
    if (by < 4) { dst = qb;  ldc = 1024; cb = c0; }
    else        { dst = kvb; ldc = 2048; cb = c0 - 1024; }
    #pragma unroll
    for (int mt = 0; mt < 8; ++mt)
        #pragma unroll
        for (int nt = 0; nt < 4; ++nt) {
            int col = cb + wn * 64 + nt * 16 + l15;
            #pragma unroll
            for (int rg = 0; rg < 4; ++rg) {
                int row = r0 + wm * 128 + mt * 16 + quad * 4 + rg;
                dst[(size_t)row * ldc + col] = f2bf(acc[mt][nt][rg]);
            }
        }
}

// ---------------- Kernel 3: kv[b,d] = sum_t k*v*rsqrt(kssq) (R9 measured form) ----------------
__global__ __launch_bounds__(512)
void kv_reduce(const u16* __restrict__ kvb, const float* __restrict__ kssq,
               float* __restrict__ kv)
{
    __shared__ float red[3][1024];
    int d  = (threadIdx.x & 127) * 8;
    int rp = threadIdx.x >> 7;                 // 0..3
    int b  = blockIdx.y;                       // 0..3
    int t0 = blockIdx.x * 64;                  // 128 t-chunks of 64 rows
    float a[8];
    #pragma unroll
    for (int e = 0; e < 8; ++e) a[e] = 0.0f;
    #pragma unroll 4
    for (int r = rp; r < 64; r += 4) {
        int row = b * T_DIM + t0 + r;
        float kin = rsqrtf(kssq[row]);
        short8 k8 = *reinterpret_cast<const short8*>(kvb + (size_t)row * 2048 + d);
        short8 v8 = *reinterpret_cast<const short8*>(kvb + (size_t)row * 2048 + 1024 + d);
        #pragma unroll
        for (int e = 0; e < 8; ++e)
            a[e] += bf2f((u16)k8[e]) * bf2f((u16)v8[e]) * kin;
    }
    if (rp) {
        #pragma unroll
        for (int e = 0; e < 8; ++e) red[rp - 1][d + e] = a[e];
    }
    __syncthreads();
    if (!rp) {
        #pragma unroll
        for (int e = 0; e < 8; ++e)
            atomicAdd(&kv[b * D_DIM + d + e],
                      a[e] + red[0][d + e] + red[1][d + e] + red[2][d + e]);
    }
}

// ---------------- Kernel 4: out = q*rsqrt(qssq)*kv*scale + bias (R9 measured form) ----------------
__global__ void finalize(const u16* __restrict__ qb, const float* __restrict__ qssq,
                         const float* __restrict__ kv, const float* __restrict__ scale,
                         const float* __restrict__ bias, float* __restrict__ out)
{
    size_t idx = (size_t)blockIdx.x * 256 + threadIdx.x;   // vec8 index
    int row = (int)(idx >> 7);
    int dv  = ((int)idx & 127) * 8;
    int b   = row >> 13;
    float qi = rsqrtf(qssq[row]);
    short8 qv = *reinterpret_cast<const short8*>(qb + (size_t)row * D_DIM + dv);
    const float* kvp = kv + b * D_DIM + dv;
    const float* sp  = scale + dv;
    const float* bp  = bias + dv;
    float4 o0, o1;
    o0.x = bf2f((u16)qv[0]) * qi * kvp[0] * sp[0] + bp[0];
    o0.y = bf2f((u16)qv[1]) * qi * kvp[1] * sp[1] + bp[1];
    o0.z = bf2f((u16)qv[2]) * qi * kvp[2] * sp[2] + bp[2];
    o0.w = bf2f((u16)qv[3]) * qi * kvp[3] * sp[3] + bp[3];
    o1.x = bf2f((u16)qv[4]) * qi * kvp[4] * sp[4] + bp[4];
    o1.y = bf2f((u16)qv[5]) * qi * kvp[5] * sp[5] + bp[5];
    o1.z = bf2f((u16)qv[6]) * qi * kvp[6] * sp[6] + bp[6];
    o1.w = bf2f((u16)qv[7]) * qi * kvp[7] * sp[7] + bp[7];
    float* op = out + (size_t)row * D_DIM + dv;
    *reinterpret_cast<float4*>(op)     = o0;
    *reinterpret_cast<float4*>(op + 4) = o1;
}

extern "C" void kernel_launch(void* const* d_in, const int* in_sizes, int n_in,
                              void* d_out, int out_size, void* d_ws, size_t ws_size,
                              hipStream_t stream) {
    const float* x     = (const float*)d_in[0];
    const float* W     = (const float*)d_in[1];
    const float* bqkv  = (const float*)d_in[2];
    const float* scale = (const float*)d_in[3];
    const float* bias  = (const float*)d_in[4];
    float* out = (float*)d_out;

    // d_out doubles as scratch until finalize: xb (64 MB) + WT (6 MB) < 128 MB
    u16* xb = (u16*)d_out;
    u16* WT = (u16*)((char*)d_out + 67108864);

    char* ws = (char*)d_ws;
    u16*   qb   = (u16*)ws;                         //  67,108,864 B
    u16*   kvb  = (u16*)(ws + 67108864);            // 134,217,728 B
    float* qssq = (float*)(ws + 201326592);         //     131,072 B
    float* kssq = (float*)(ws + 201457664);         //     131,072 B
    float* kv   = (float*)(ws + 201588736);         //      16,384 B
    // qssq/kssq/kv contiguous: zero-filled by prep (272*256 floats)

    prep     <<<dim3(16384 + 3072), dim3(256), 0, stream>>>(x, xb, W, WT, qssq);
    gemm_k   <<<dim3(ROWS / BM, 12), dim3(512), 0, stream>>>(xb, WT, bqkv, qb, kvb, qssq, kssq);
    kv_reduce<<<dim3(T_DIM / 64, 4), dim3(512), 0, stream>>>(kvb, kssq, kv);
    finalize <<<dim3(ROWS * (D_DIM / 8) / 256), dim3(256), 0, stream>>>(qb, qssq, kv, scale, bias, out);
}